// Round 5
// baseline (369.359 us; speedup 1.0000x reference)
//
#include <hip/hip_runtime.h>

#define NNODES 50000
#define NEDGES 800000
#define DIM 96
#define LLDIM 64
#define NRELS 3            // metapath relations 0,1,2
#define SCAN_N (NRELS * NNODES)

// ---------------- CSR build ----------------

__global__ void hist_kernel(const int* __restrict__ ei, const int* __restrict__ et,
                            int* __restrict__ deg) {
    int e = blockIdx.x * 256 + threadIdx.x;
    if (e >= NEDGES) return;
    int r = et[e];
    if (r < NRELS) atomicAdd(&deg[r * NNODES + ei[e]], 1);
}

__global__ void scan1_kernel(const int* __restrict__ in, int* __restrict__ out,
                             int* __restrict__ partials, int n) {
    __shared__ int sdata[256];
    int tid = threadIdx.x;
    int base = blockIdx.x * 1024 + tid * 4;
    int v0 = (base + 0 < n) ? in[base + 0] : 0;
    int v1 = (base + 1 < n) ? in[base + 1] : 0;
    int v2 = (base + 2 < n) ? in[base + 2] : 0;
    int v3 = (base + 3 < n) ? in[base + 3] : 0;
    int tsum = v0 + v1 + v2 + v3;
    sdata[tid] = tsum;
    __syncthreads();
    for (int off = 1; off < 256; off <<= 1) {
        int x = sdata[tid];
        int y = (tid >= off) ? sdata[tid - off] : 0;
        __syncthreads();
        sdata[tid] = x + y;
        __syncthreads();
    }
    int excl = sdata[tid] - tsum;
    if (tid == 255) partials[blockIdx.x] = sdata[255];
    if (base + 0 < n) out[base + 0] = excl;
    excl += v0;
    if (base + 1 < n) out[base + 1] = excl;
    excl += v1;
    if (base + 2 < n) out[base + 2] = excl;
    excl += v2;
    if (base + 3 < n) out[base + 3] = excl;
}

__global__ void scan2_kernel(int* __restrict__ partials, int nb) {
    __shared__ int sdata[256];
    int tid = threadIdx.x;
    int v = (tid < nb) ? partials[tid] : 0;
    sdata[tid] = v;
    __syncthreads();
    for (int off = 1; off < 256; off <<= 1) {
        int x = sdata[tid];
        int y = (tid >= off) ? sdata[tid - off] : 0;
        __syncthreads();
        sdata[tid] = x + y;
        __syncthreads();
    }
    partials[tid] = sdata[tid] - v;   // exclusive
}

// writes final row_start AND initializes the fill cursor
__global__ void scan3_kernel(int* __restrict__ rs, int* __restrict__ cursor,
                             const int* __restrict__ partials, int n) {
    int idx = blockIdx.x * 256 + threadIdx.x;
    if (idx < n) {
        int v = rs[idx] + partials[idx >> 10];
        rs[idx] = v;
        cursor[idx] = v;
    }
}

__global__ void fill_kernel(const int* __restrict__ ei, const int* __restrict__ et,
                            int* __restrict__ cursor, int* __restrict__ col) {
    int e = blockIdx.x * 256 + threadIdx.x;
    if (e >= NEDGES) return;
    int r = et[e];
    if (r < NRELS) {
        int pos = atomicAdd(&cursor[r * NNODES + ei[e]], 1);
        col[pos] = ei[NEDGES + e];
    }
}

// ---------------- fused yz GEMM: y = h@W, z = h@R (one A-stage) ----------------
// Block: 64 nodes x 192 cols (96 y | 96 z), 192 threads, 8 nodes x 8 cols/thread.
// LDS hot loop: 4 x ds_read_b128 per 64 FMA (1 B/FLOP) -> LDS pipe ~ VALU balanced.

__global__ __launch_bounds__(192) void yz_gemm_kernel(
    const float* __restrict__ h, const float* __restrict__ W,
    const float* __restrict__ R, float* __restrict__ y, float* __restrict__ z) {
    __shared__ __align__(16) float Alds[96][72];    // [k][node], 27.6 KB
    __shared__ __align__(16) float Wlds[24][200];   // chunk: [k][col 0..95=W,96..191=R], 19.2 KB
    int tid = threadIdx.x;
    int n0 = blockIdx.x * 64;
    int nq = tid & 7;        // node oct: nodes nq*8 .. nq*8+7
    int c8 = tid >> 3;       // col oct 0..23: cols c8*8 .. c8*8+7 (of 192)

    float acc[8][8];
#pragma unroll
    for (int j = 0; j < 8; ++j)
#pragma unroll
        for (int c = 0; c < 8; ++c) acc[j][c] = 0.0f;

    // stage A transposed once: 64 rows x 24 float4
    for (int idx = tid; idx < 64 * 24; idx += 192) {
        int row = idx & 63;
        int kq = idx >> 6;
        int rn = n0 + row;
        if (rn >= NNODES) rn = NNODES - 1;
        float4 v = *(const float4*)(h + (size_t)rn * DIM + kq * 4);
        Alds[kq * 4 + 0][row] = v.x;
        Alds[kq * 4 + 1][row] = v.y;
        Alds[kq * 4 + 2][row] = v.z;
        Alds[kq * 4 + 3][row] = v.w;
    }

    for (int chunk = 0; chunk < 4; ++chunk) {
        int kc = chunk * 24;
        __syncthreads();   // Wlds reuse safe (also covers A-stage on first iter)
        // stage W|R chunk: 24 k-rows x 48 float4 (24 from W, 24 from R)
        for (int idx = tid; idx < 24 * 48; idx += 192) {
            int kr = idx / 48;
            int cq = idx % 48;
            const float* src = (cq < 24)
                ? (W + (size_t)(kc + kr) * DIM + cq * 4)
                : (R + (size_t)(kc + kr) * DIM + (cq - 24) * 4);
            *(float4*)&Wlds[kr][cq * 4] = *(const float4*)src;
        }
        __syncthreads();
#pragma unroll 8
        for (int k = 0; k < 24; ++k) {
            float4 a0 = *(float4*)&Alds[kc + k][nq * 8];
            float4 a1 = *(float4*)&Alds[kc + k][nq * 8 + 4];
            float4 w0 = *(float4*)&Wlds[k][c8 * 8];
            float4 w1 = *(float4*)&Wlds[k][c8 * 8 + 4];
            float av[8] = {a0.x, a0.y, a0.z, a0.w, a1.x, a1.y, a1.z, a1.w};
            float wv[8] = {w0.x, w0.y, w0.z, w0.w, w1.x, w1.y, w1.z, w1.w};
#pragma unroll
            for (int j = 0; j < 8; ++j)
#pragma unroll
                for (int c = 0; c < 8; ++c) acc[j][c] += av[j] * wv[c];
        }
    }

    // store: c8 0..11 -> y, c8 12..23 -> z
    float* outp = (c8 < 12) ? y : z;
    int cb = ((c8 < 12) ? c8 : (c8 - 12)) * 8;
#pragma unroll
    for (int j = 0; j < 8; ++j) {
        int n = n0 + nq * 8 + j;
        if (n < NNODES) {
            float4 r0 = make_float4(acc[j][0], acc[j][1], acc[j][2], acc[j][3]);
            float4 r1 = make_float4(acc[j][4], acc[j][5], acc[j][6], acc[j][7]);
            *(float4*)(outp + (size_t)n * DIM + cb)     = r0;
            *(float4*)(outp + (size_t)n * DIM + cb + 4) = r1;
        }
    }
}

// ---------------- gather + epilogue: out[n] = relu(mean_{d in N(n)} y[d] + z[n] + b) ----
// z lives in the SAME buffer as out (in-place read-modify-write, node-local).

__global__ __launch_bounds__(256) void gather_epi_kernel(
    const float* __restrict__ y, const int* __restrict__ rs,
    const int* __restrict__ re, const int* __restrict__ col,
    const float* __restrict__ b, float* __restrict__ out) {
    int node = blockIdx.x * 8 + (threadIdx.x >> 5);
    if (node >= NNODES) return;
    int l = threadIdx.x & 31;
    if (l >= 24) return;
    int s = rs[node];
    int e = re[node];
    float4 acc = make_float4(0.f, 0.f, 0.f, 0.f);
    int i = s;
    for (; i + 1 < e; i += 2) {
        const float4* r0 = (const float4*)(y + (size_t)col[i] * DIM);
        const float4* r1 = (const float4*)(y + (size_t)col[i + 1] * DIM);
        float4 u = r0[l];
        float4 v = r1[l];
        acc.x += u.x + v.x; acc.y += u.y + v.y;
        acc.z += u.z + v.z; acc.w += u.w + v.w;
    }
    if (i < e) {
        float4 u = ((const float4*)(y + (size_t)col[i] * DIM))[l];
        acc.x += u.x; acc.y += u.y; acc.z += u.z; acc.w += u.w;
    }
    float scl = 1.0f / fmaxf((float)(e - s), 1.0f);
    float4 zv = ((const float4*)(out + (size_t)node * DIM))[l];
    float4 bv = ((const float4*)b)[l];
    float4 r;
    r.x = fmaxf(acc.x * scl + zv.x + bv.x, 0.0f);
    r.y = fmaxf(acc.y * scl + zv.y + bv.y, 0.0f);
    r.z = fmaxf(acc.z * scl + zv.z + bv.z, 0.0f);
    r.w = fmaxf(acc.w * scl + zv.w + bv.w, 0.0f);
    ((float4*)(out + (size_t)node * DIM))[l] = r;
}

// ---------------- final linear: out = h @ lin_w + lin_b ----------------

__global__ __launch_bounds__(256) void final_kernel(
    const float* __restrict__ h, const float* __restrict__ LW,
    const float* __restrict__ LB, float* __restrict__ out) {
    __shared__ __align__(16) float Alds[96][68];
    __shared__ __align__(16) float Wlds[96][68];
    int tid = threadIdx.x;
    int q = tid & 15;        // col quad
    int nb = tid >> 4;       // node quad
    int n0 = blockIdx.x * 64;

    for (int idx = tid; idx < 64 * 24; idx += 256) {
        int row = idx & 63;
        int kq = idx >> 6;
        int rn = n0 + row;
        if (rn >= NNODES) rn = NNODES - 1;
        float4 v = *(const float4*)(h + (size_t)rn * DIM + kq * 4);
        Alds[kq * 4 + 0][row] = v.x;
        Alds[kq * 4 + 1][row] = v.y;
        Alds[kq * 4 + 2][row] = v.z;
        Alds[kq * 4 + 3][row] = v.w;
    }
    for (int idx = tid; idx < 96 * 16; idx += 256) {
        int kr = idx >> 4;
        int cq = idx & 15;
        *(float4*)&Wlds[kr][cq * 4] = *(const float4*)(LW + (size_t)kr * LLDIM + cq * 4);
    }
    __syncthreads();

    float acc[4][4];
#pragma unroll
    for (int j = 0; j < 4; ++j)
#pragma unroll
        for (int c = 0; c < 4; ++c) acc[j][c] = 0.0f;

#pragma unroll 4
    for (int k = 0; k < 96; ++k) {
        float4 a4 = *(float4*)&Alds[k][nb * 4];
        float4 w4 = *(float4*)&Wlds[k][q * 4];
        acc[0][0] += a4.x * w4.x; acc[0][1] += a4.x * w4.y;
        acc[0][2] += a4.x * w4.z; acc[0][3] += a4.x * w4.w;
        acc[1][0] += a4.y * w4.x; acc[1][1] += a4.y * w4.y;
        acc[1][2] += a4.y * w4.z; acc[1][3] += a4.y * w4.w;
        acc[2][0] += a4.z * w4.x; acc[2][1] += a4.z * w4.y;
        acc[2][2] += a4.z * w4.z; acc[2][3] += a4.z * w4.w;
        acc[3][0] += a4.w * w4.x; acc[3][1] += a4.w * w4.y;
        acc[3][2] += a4.w * w4.z; acc[3][3] += a4.w * w4.w;
    }

    float4 bv = *(const float4*)(LB + q * 4);
    int nbase = n0 + nb * 4;
#pragma unroll
    for (int j = 0; j < 4; ++j) {
        int n = nbase + j;
        if (n < NNODES) {
            float4 r;
            r.x = acc[j][0] + bv.x;
            r.y = acc[j][1] + bv.y;
            r.z = acc[j][2] + bv.z;
            r.w = acc[j][3] + bv.w;
            *(float4*)(out + (size_t)n * LLDIM + q * 4) = r;
        }
    }
}

extern "C" void kernel_launch(void* const* d_in, const int* in_sizes, int n_in,
                              void* d_out, int out_size, void* d_ws, size_t ws_size,
                              hipStream_t stream) {
    const float* x     = (const float*)d_in[0];
    const int*   ei    = (const int*)d_in[1];
    const int*   et    = (const int*)d_in[2];
    const float* w1    = (const float*)d_in[3];
    const float* root1 = (const float*)d_in[4];
    const float* b1    = (const float*)d_in[5];
    const float* w2    = (const float*)d_in[6];
    const float* root2 = (const float*)d_in[7];
    const float* b2    = (const float*)d_in[8];
    const float* lin_w = (const float*)d_in[9];
    const float* lin_b = (const float*)d_in[10];

    float* bufA = (float*)d_ws;                      // N*96  (z/out, layers 0 & 2)
    float* bufB = bufA + (size_t)NNODES * DIM;       // N*96  (z/out, layer 1)
    float* ybuf = bufB + (size_t)NNODES * DIM;       // N*96  (y, reused per layer)
    int* deg       = (int*)(ybuf + (size_t)NNODES * DIM);
    int* row_start = deg + SCAN_N;
    int* row_end   = row_start + SCAN_N;             // fill cursor -> row ends
    int* col       = row_end + SCAN_N;               // up to NEDGES
    int* partials  = col + NEDGES;                   // 256

    const int edge_blocks = (NEDGES + 255) / 256;
    const int scan_blocks = (SCAN_N + 1023) / 1024;
    const int node_tiles  = (NNODES + 63) / 64;      // 782
    const int gath_blocks = (NNODES + 7) / 8;        // 6250

    // ---- CSR build (edge structure identical for all 3 layers) ----
    hipMemsetAsync(deg, 0, SCAN_N * sizeof(int), stream);
    hist_kernel<<<edge_blocks, 256, 0, stream>>>(ei, et, deg);
    scan1_kernel<<<scan_blocks, 256, 0, stream>>>(deg, row_start, partials, SCAN_N);
    scan2_kernel<<<1, 256, 0, stream>>>(partials, scan_blocks);
    scan3_kernel<<<(SCAN_N + 255) / 256, 256, 0, stream>>>(row_start, row_end, partials, SCAN_N);
    fill_kernel<<<edge_blocks, 256, 0, stream>>>(ei, et, row_end, col);

    // ---- Layer 0: rel 0, w1[0], root1, b1 :  x -> bufA ----
    yz_gemm_kernel<<<node_tiles, 192, 0, stream>>>(x, w1, root1, ybuf, bufA);
    gather_epi_kernel<<<gath_blocks, 256, 0, stream>>>(
        ybuf, row_start + 0 * NNODES, row_end + 0 * NNODES, col, b1, bufA);

    // ---- Layer 1: rel 1, w2[1], root2, b2 :  bufA -> bufB ----
    yz_gemm_kernel<<<node_tiles, 192, 0, stream>>>(
        bufA, w2 + (size_t)1 * DIM * DIM, root2, ybuf, bufB);
    gather_epi_kernel<<<gath_blocks, 256, 0, stream>>>(
        ybuf, row_start + 1 * NNODES, row_end + 1 * NNODES, col, b2, bufB);

    // ---- Layer 2: rel 2, w2[2], root2, b2 :  bufB -> bufA ----
    yz_gemm_kernel<<<node_tiles, 192, 0, stream>>>(
        bufB, w2 + (size_t)2 * DIM * DIM, root2, ybuf, bufA);
    gather_epi_kernel<<<gath_blocks, 256, 0, stream>>>(
        ybuf, row_start + 2 * NNODES, row_end + 2 * NNODES, col, b2, bufA);

    // ---- Final linear: bufA -> d_out ----
    final_kernel<<<node_tiles, 256, 0, stream>>>(bufA, lin_w, lin_b, (float*)d_out);
}

// Round 6
// 349.630 us; speedup vs baseline: 1.0564x; 1.0564x over previous
//
#include <hip/hip_runtime.h>

#define NNODES 50000
#define NEDGES 800000
#define DIM 96
#define LLDIM 64
#define NRELS 3
#define SCAN_N (NRELS * NNODES)
#define NPAD 50176          // 49 * 1024, node dim padded for tgemm tiles

// ---------------- CSR build ----------------

__global__ void hist_kernel(const int* __restrict__ ei, const int* __restrict__ et,
                            int* __restrict__ deg) {
    int e = blockIdx.x * 256 + threadIdx.x;
    if (e >= NEDGES) return;
    int r = et[e];
    if (r < NRELS) atomicAdd(&deg[r * NNODES + ei[e]], 1);
}

__global__ void scan1_kernel(const int* __restrict__ in, int* __restrict__ out,
                             int* __restrict__ partials, int n) {
    __shared__ int sdata[256];
    int tid = threadIdx.x;
    int base = blockIdx.x * 1024 + tid * 4;
    int v0 = (base + 0 < n) ? in[base + 0] : 0;
    int v1 = (base + 1 < n) ? in[base + 1] : 0;
    int v2 = (base + 2 < n) ? in[base + 2] : 0;
    int v3 = (base + 3 < n) ? in[base + 3] : 0;
    int tsum = v0 + v1 + v2 + v3;
    sdata[tid] = tsum;
    __syncthreads();
    for (int off = 1; off < 256; off <<= 1) {
        int x = sdata[tid];
        int y = (tid >= off) ? sdata[tid - off] : 0;
        __syncthreads();
        sdata[tid] = x + y;
        __syncthreads();
    }
    int excl = sdata[tid] - tsum;
    if (tid == 255) partials[blockIdx.x] = sdata[255];
    if (base + 0 < n) out[base + 0] = excl;
    excl += v0;
    if (base + 1 < n) out[base + 1] = excl;
    excl += v1;
    if (base + 2 < n) out[base + 2] = excl;
    excl += v2;
    if (base + 3 < n) out[base + 3] = excl;
}

__global__ void scan2_kernel(int* __restrict__ partials, int nb) {
    __shared__ int sdata[256];
    int tid = threadIdx.x;
    int v = (tid < nb) ? partials[tid] : 0;
    sdata[tid] = v;
    __syncthreads();
    for (int off = 1; off < 256; off <<= 1) {
        int x = sdata[tid];
        int y = (tid >= off) ? sdata[tid - off] : 0;
        __syncthreads();
        sdata[tid] = x + y;
        __syncthreads();
    }
    partials[tid] = sdata[tid] - v;   // exclusive
}

__global__ void scan3_kernel(int* __restrict__ rs, int* __restrict__ cursor,
                             const int* __restrict__ partials, int n) {
    int idx = blockIdx.x * 256 + threadIdx.x;
    if (idx < n) {
        int v = rs[idx] + partials[idx >> 10];
        rs[idx] = v;
        cursor[idx] = v;
    }
}

__global__ void fill_kernel(const int* __restrict__ ei, const int* __restrict__ et,
                            int* __restrict__ cursor, int* __restrict__ col) {
    int e = blockIdx.x * 256 + threadIdx.x;
    if (e >= NEDGES) return;
    int r = et[e];
    if (r < NRELS) {
        int pos = atomicAdd(&cursor[r * NNODES + ei[e]], 1);
        col[pos] = ei[NEDGES + e];
    }
}

// ---------------- transpose: x[N][96] -> hT[96][NPAD] ----------------

__global__ __launch_bounds__(256) void transpose_kernel(
    const float* __restrict__ x, float* __restrict__ hT) {
    __shared__ float t[32][33];
    int n0 = blockIdx.x * 32;
    int c0 = blockIdx.y * 32;
    int tx = threadIdx.x & 31;
    int ty = threadIdx.x >> 5;   // 0..7
    for (int r = ty; r < 32; r += 8) {
        int n = n0 + r;
        if (n < NNODES) t[r][tx] = x[(size_t)n * DIM + c0 + tx];
    }
    __syncthreads();
    for (int r = ty; r < 32; r += 8) {
        int n = n0 + tx;
        if (n < NNODES) hT[(size_t)(c0 + r) * NPAD + n] = t[tx][r];
    }
}

// ---------------- tgemm: y = h@W, z = h@R from hT (no LDS) ----------------
// Block: 1024 nodes x 8 cols, 256 threads; thread = 4 nodes x 8 cols.
// Per k: 1 coalesced float4 load of hT + wave-uniform W row slice (-> s_load)
// + 32 v_fmac. Grid 49*24=1176, ~18 waves/CU.

__global__ __launch_bounds__(256) void tgemm_kernel(
    const float* __restrict__ hT, const float* __restrict__ W,
    const float* __restrict__ R, float* __restrict__ y, float* __restrict__ z) {
    int nb = blockIdx.x / 24;
    int cg = blockIdx.x % 24;          // consecutive blocks share the hT slice
    const float* B = (cg < 12) ? W : R;
    float* out = (cg < 12) ? y : z;
    int c0 = ((cg < 12) ? cg : cg - 12) * 8;
    int nbase = nb * 1024 + threadIdx.x * 4;

    float acc[4][8];
#pragma unroll
    for (int j = 0; j < 4; ++j)
#pragma unroll
        for (int c = 0; c < 8; ++c) acc[j][c] = 0.0f;

    const float* hp = hT + nbase;
#pragma unroll 8
    for (int k = 0; k < DIM; ++k) {
        float4 hv = *(const float4*)(hp + (size_t)k * NPAD);
        // wave-uniform reads -> scalar loads
        float4 w0 = *(const float4*)(B + (size_t)k * DIM + c0);
        float4 w1 = *(const float4*)(B + (size_t)k * DIM + c0 + 4);
        float hvv[4] = {hv.x, hv.y, hv.z, hv.w};
        float wv[8] = {w0.x, w0.y, w0.z, w0.w, w1.x, w1.y, w1.z, w1.w};
#pragma unroll
        for (int j = 0; j < 4; ++j)
#pragma unroll
            for (int c = 0; c < 8; ++c) acc[j][c] += hvv[j] * wv[c];
    }

#pragma unroll
    for (int j = 0; j < 4; ++j) {
        int n = nbase + j;
        if (n < NNODES) {
            float4 r0 = make_float4(acc[j][0], acc[j][1], acc[j][2], acc[j][3]);
            float4 r1 = make_float4(acc[j][4], acc[j][5], acc[j][6], acc[j][7]);
            *(float4*)(out + (size_t)n * DIM + c0)     = r0;
            *(float4*)(out + (size_t)n * DIM + c0 + 4) = r1;
        }
    }
}

// ---------------- gather + epilogue (+ optional transposed write to hT) ----------
// out[n] = relu(mean_{d in N(n)} y[d] + z[n] + b);  z lives in `out` (in place).
// If writeT: also store the result transposed into hT for the next tgemm.

__global__ __launch_bounds__(256) void gather_epi_kernel(
    const float* __restrict__ y, const int* __restrict__ rs,
    const int* __restrict__ re, const int* __restrict__ col,
    const float* __restrict__ b, float* __restrict__ out,
    float* __restrict__ hT, int writeT) {
    __shared__ __align__(16) float lds[8][100];
    int g = threadIdx.x >> 5;                 // 0..7 node within block
    int node = blockIdx.x * 8 + g;            // 6250*8 = 50000 exact, no tail
    int l = threadIdx.x & 31;

    if (l < 24) {
        int s = rs[node];
        int e = re[node];
        float4 acc = make_float4(0.f, 0.f, 0.f, 0.f);
        int i = s;
        for (; i + 1 < e; i += 2) {
            const float4* r0 = (const float4*)(y + (size_t)col[i] * DIM);
            const float4* r1 = (const float4*)(y + (size_t)col[i + 1] * DIM);
            float4 u = r0[l];
            float4 v = r1[l];
            acc.x += u.x + v.x; acc.y += u.y + v.y;
            acc.z += u.z + v.z; acc.w += u.w + v.w;
        }
        if (i < e) {
            float4 u = ((const float4*)(y + (size_t)col[i] * DIM))[l];
            acc.x += u.x; acc.y += u.y; acc.z += u.z; acc.w += u.w;
        }
        float scl = 1.0f / fmaxf((float)(e - s), 1.0f);
        float4 zv = ((const float4*)(out + (size_t)node * DIM))[l];
        float4 bv = ((const float4*)b)[l];
        float4 r;
        r.x = fmaxf(acc.x * scl + zv.x + bv.x, 0.0f);
        r.y = fmaxf(acc.y * scl + zv.y + bv.y, 0.0f);
        r.z = fmaxf(acc.z * scl + zv.z + bv.z, 0.0f);
        r.w = fmaxf(acc.w * scl + zv.w + bv.w, 0.0f);
        ((float4*)(out + (size_t)node * DIM))[l] = r;
        *(float4*)&lds[g][l * 4] = r;
    }
    if (writeT) {
        __syncthreads();
        int n0 = blockIdx.x * 8;
        for (int idx = threadIdx.x; idx < 8 * DIM; idx += 256) {
            int c = idx >> 3;
            int j = idx & 7;
            hT[(size_t)c * NPAD + n0 + j] = lds[j][c];
        }
    }
}

// ---------------- final linear: out = h @ lin_w + lin_b ----------------

__global__ __launch_bounds__(256) void final_kernel(
    const float* __restrict__ h, const float* __restrict__ LW,
    const float* __restrict__ LB, float* __restrict__ out) {
    __shared__ __align__(16) float Alds[96][68];
    __shared__ __align__(16) float Wlds[96][68];
    int tid = threadIdx.x;
    int q = tid & 15;
    int nb = tid >> 4;
    int n0 = blockIdx.x * 64;

    for (int idx = tid; idx < 64 * 24; idx += 256) {
        int row = idx & 63;
        int kq = idx >> 6;
        int rn = n0 + row;
        if (rn >= NNODES) rn = NNODES - 1;
        float4 v = *(const float4*)(h + (size_t)rn * DIM + kq * 4);
        Alds[kq * 4 + 0][row] = v.x;
        Alds[kq * 4 + 1][row] = v.y;
        Alds[kq * 4 + 2][row] = v.z;
        Alds[kq * 4 + 3][row] = v.w;
    }
    for (int idx = tid; idx < 96 * 16; idx += 256) {
        int kr = idx >> 4;
        int cq = idx & 15;
        *(float4*)&Wlds[kr][cq * 4] = *(const float4*)(LW + (size_t)kr * LLDIM + cq * 4);
    }
    __syncthreads();

    float acc[4][4];
#pragma unroll
    for (int j = 0; j < 4; ++j)
#pragma unroll
        for (int c = 0; c < 4; ++c) acc[j][c] = 0.0f;

#pragma unroll 4
    for (int k = 0; k < 96; ++k) {
        float4 a4 = *(float4*)&Alds[k][nb * 4];
        float4 w4 = *(float4*)&Wlds[k][q * 4];
        acc[0][0] += a4.x * w4.x; acc[0][1] += a4.x * w4.y;
        acc[0][2] += a4.x * w4.z; acc[0][3] += a4.x * w4.w;
        acc[1][0] += a4.y * w4.x; acc[1][1] += a4.y * w4.y;
        acc[1][2] += a4.y * w4.z; acc[1][3] += a4.y * w4.w;
        acc[2][0] += a4.z * w4.x; acc[2][1] += a4.z * w4.y;
        acc[2][2] += a4.z * w4.z; acc[2][3] += a4.z * w4.w;
        acc[3][0] += a4.w * w4.x; acc[3][1] += a4.w * w4.y;
        acc[3][2] += a4.w * w4.z; acc[3][3] += a4.w * w4.w;
    }

    float4 bv = *(const float4*)(LB + q * 4);
    int nbase = n0 + nb * 4;
#pragma unroll
    for (int j = 0; j < 4; ++j) {
        int n = nbase + j;
        if (n < NNODES) {
            float4 r;
            r.x = acc[j][0] + bv.x;
            r.y = acc[j][1] + bv.y;
            r.z = acc[j][2] + bv.z;
            r.w = acc[j][3] + bv.w;
            *(float4*)(out + (size_t)n * LLDIM + q * 4) = r;
        }
    }
}

extern "C" void kernel_launch(void* const* d_in, const int* in_sizes, int n_in,
                              void* d_out, int out_size, void* d_ws, size_t ws_size,
                              hipStream_t stream) {
    const float* x     = (const float*)d_in[0];
    const int*   ei    = (const int*)d_in[1];
    const int*   et    = (const int*)d_in[2];
    const float* w1    = (const float*)d_in[3];
    const float* root1 = (const float*)d_in[4];
    const float* b1    = (const float*)d_in[5];
    const float* w2    = (const float*)d_in[6];
    const float* root2 = (const float*)d_in[7];
    const float* b2    = (const float*)d_in[8];
    const float* lin_w = (const float*)d_in[9];
    const float* lin_b = (const float*)d_in[10];

    float* outRM = (float*)d_ws;                       // N*96  (z then layer out)
    float* ybuf  = outRM + (size_t)NNODES * DIM;       // N*96
    float* hT    = ybuf + (size_t)NNODES * DIM;        // 96*NPAD
    int* deg       = (int*)(hT + (size_t)DIM * NPAD);
    int* row_start = deg + SCAN_N;
    int* row_end   = row_start + SCAN_N;
    int* col       = row_end + SCAN_N;                 // up to NEDGES
    int* partials  = col + NEDGES;                     // 256

    const int edge_blocks = (NEDGES + 255) / 256;
    const int scan_blocks = (SCAN_N + 1023) / 1024;
    const int node_tiles  = (NNODES + 63) / 64;        // 782 (final kernel)
    const int gath_blocks = NNODES / 8;                // 6250 exact
    const int tg_blocks   = 49 * 24;                   // 1176
    const dim3 tr_grid((NNODES + 31) / 32, DIM / 32);  // 1563 x 3

    // ---- CSR build ----
    hipMemsetAsync(deg, 0, SCAN_N * sizeof(int), stream);
    hist_kernel<<<edge_blocks, 256, 0, stream>>>(ei, et, deg);
    scan1_kernel<<<scan_blocks, 256, 0, stream>>>(deg, row_start, partials, SCAN_N);
    scan2_kernel<<<1, 256, 0, stream>>>(partials, scan_blocks);
    scan3_kernel<<<(SCAN_N + 255) / 256, 256, 0, stream>>>(row_start, row_end, partials, SCAN_N);
    fill_kernel<<<edge_blocks, 256, 0, stream>>>(ei, et, row_end, col);

    // ---- seed transposed input ----
    transpose_kernel<<<tr_grid, 256, 0, stream>>>(x, hT);

    // ---- Layer 0: rel 0 ----
    tgemm_kernel<<<tg_blocks, 256, 0, stream>>>(hT, w1, root1, ybuf, outRM);
    gather_epi_kernel<<<gath_blocks, 256, 0, stream>>>(
        ybuf, row_start + 0 * NNODES, row_end + 0 * NNODES, col, b1, outRM, hT, 1);

    // ---- Layer 1: rel 1 ----
    tgemm_kernel<<<tg_blocks, 256, 0, stream>>>(
        hT, w2 + (size_t)1 * DIM * DIM, root2, ybuf, outRM);
    gather_epi_kernel<<<gath_blocks, 256, 0, stream>>>(
        ybuf, row_start + 1 * NNODES, row_end + 1 * NNODES, col, b2, outRM, hT, 1);

    // ---- Layer 2: rel 2 (no transposed write needed) ----
    tgemm_kernel<<<tg_blocks, 256, 0, stream>>>(
        hT, w2 + (size_t)2 * DIM * DIM, root2, ybuf, outRM);
    gather_epi_kernel<<<gath_blocks, 256, 0, stream>>>(
        ybuf, row_start + 2 * NNODES, row_end + 2 * NNODES, col, b2, outRM, hT, 0);

    // ---- Final linear ----
    final_kernel<<<node_tiles, 256, 0, stream>>>(outRM, lin_w, lin_b, (float*)d_out);
}

// Round 7
// 347.425 us; speedup vs baseline: 1.0631x; 1.0063x over previous
//
#include <hip/hip_runtime.h>

#define NNODES 50000
#define NEDGES 800000
#define DIM 96
#define LLDIM 64
#define NRELS 3
#define SCAN_N (NRELS * NNODES)
#define NPAD 50176          // 49 * 1024, node dim padded for tgemm tiles

// ---------------- CSR build ----------------

__global__ void hist_kernel(const int* __restrict__ ei, const int* __restrict__ et,
                            int* __restrict__ deg) {
    int e = blockIdx.x * 256 + threadIdx.x;
    if (e >= NEDGES) return;
    int r = et[e];
    if (r < NRELS) atomicAdd(&deg[r * NNODES + ei[e]], 1);
}

__global__ void scan1_kernel(const int* __restrict__ in, int* __restrict__ out,
                             int* __restrict__ partials, int n) {
    __shared__ int sdata[256];
    int tid = threadIdx.x;
    int base = blockIdx.x * 1024 + tid * 4;
    int v0 = (base + 0 < n) ? in[base + 0] : 0;
    int v1 = (base + 1 < n) ? in[base + 1] : 0;
    int v2 = (base + 2 < n) ? in[base + 2] : 0;
    int v3 = (base + 3 < n) ? in[base + 3] : 0;
    int tsum = v0 + v1 + v2 + v3;
    sdata[tid] = tsum;
    __syncthreads();
    for (int off = 1; off < 256; off <<= 1) {
        int x = sdata[tid];
        int y = (tid >= off) ? sdata[tid - off] : 0;
        __syncthreads();
        sdata[tid] = x + y;
        __syncthreads();
    }
    int excl = sdata[tid] - tsum;
    if (tid == 255) partials[blockIdx.x] = sdata[255];
    if (base + 0 < n) out[base + 0] = excl;
    excl += v0;
    if (base + 1 < n) out[base + 1] = excl;
    excl += v1;
    if (base + 2 < n) out[base + 2] = excl;
    excl += v2;
    if (base + 3 < n) out[base + 3] = excl;
}

__global__ void scan2_kernel(int* __restrict__ partials, int nb) {
    __shared__ int sdata[256];
    int tid = threadIdx.x;
    int v = (tid < nb) ? partials[tid] : 0;
    sdata[tid] = v;
    __syncthreads();
    for (int off = 1; off < 256; off <<= 1) {
        int x = sdata[tid];
        int y = (tid >= off) ? sdata[tid - off] : 0;
        __syncthreads();
        sdata[tid] = x + y;
        __syncthreads();
    }
    partials[tid] = sdata[tid] - v;   // exclusive
}

__global__ void scan3_kernel(int* __restrict__ rs, int* __restrict__ cursor,
                             const int* __restrict__ partials, int n) {
    int idx = blockIdx.x * 256 + threadIdx.x;
    if (idx < n) {
        int v = rs[idx] + partials[idx >> 10];
        rs[idx] = v;
        cursor[idx] = v;
    }
}

__global__ void fill_kernel(const int* __restrict__ ei, const int* __restrict__ et,
                            int* __restrict__ cursor, int* __restrict__ col) {
    int e = blockIdx.x * 256 + threadIdx.x;
    if (e >= NEDGES) return;
    int r = et[e];
    if (r < NRELS) {
        int pos = atomicAdd(&cursor[r * NNODES + ei[e]], 1);
        col[pos] = ei[NEDGES + e];
    }
}

// ---------------- transpose: x[N][96] -> hT[96][NPAD] ----------------

__global__ __launch_bounds__(256) void transpose_kernel(
    const float* __restrict__ x, float* __restrict__ hT) {
    __shared__ float t[32][33];
    int n0 = blockIdx.x * 32;
    int c0 = blockIdx.y * 32;
    int tx = threadIdx.x & 31;
    int ty = threadIdx.x >> 5;   // 0..7
    for (int r = ty; r < 32; r += 8) {
        int n = n0 + r;
        if (n < NNODES) t[r][tx] = x[(size_t)n * DIM + c0 + tx];
    }
    __syncthreads();
    for (int r = ty; r < 32; r += 8) {
        int n = n0 + tx;
        if (n < NNODES) hT[(size_t)(c0 + r) * NPAD + n] = t[tx][r];
    }
}

// ---------------- tgemm: y = h@W, z = h@R from hT (no LDS, XCD-swizzled) ------
// Thread = 4 nodes x 8 cols; block = 1024 nodes x 8 cols.
// XCD swizzle: all 24 col-group blocks sharing one hT slice get the same
// blockIdx%8 -> same XCD -> slice HBM-fetched once, then L2-served.
// nb padded to 56 (7 per XCD x 8); nb>=49 blocks exit.

__global__ __launch_bounds__(256) void tgemm_kernel(
    const float* __restrict__ hT, const float* __restrict__ W,
    const float* __restrict__ R, float* __restrict__ y, float* __restrict__ z) {
    int xcd = blockIdx.x & 7;
    int i = blockIdx.x >> 3;       // 0..167
    int nb = xcd * 7 + i / 24;     // 0..55
    int cg = i % 24;
    if (nb >= 49) return;

    const float* B = (cg < 12) ? W : R;
    float* out = (cg < 12) ? y : z;
    int c0 = ((cg < 12) ? cg : cg - 12) * 8;
    int nbase = nb * 1024 + threadIdx.x * 4;

    float acc[4][8];
#pragma unroll
    for (int j = 0; j < 4; ++j)
#pragma unroll
        for (int c = 0; c < 8; ++c) acc[j][c] = 0.0f;

    const float* hp = hT + nbase;
#pragma unroll 8
    for (int k = 0; k < DIM; ++k) {
        float4 hv = *(const float4*)(hp + (size_t)k * NPAD);
        // wave-uniform reads -> scalar loads
        float4 w0 = *(const float4*)(B + (size_t)k * DIM + c0);
        float4 w1 = *(const float4*)(B + (size_t)k * DIM + c0 + 4);
        float hvv[4] = {hv.x, hv.y, hv.z, hv.w};
        float wv[8] = {w0.x, w0.y, w0.z, w0.w, w1.x, w1.y, w1.z, w1.w};
#pragma unroll
        for (int j = 0; j < 4; ++j)
#pragma unroll
            for (int c = 0; c < 8; ++c) acc[j][c] += hvv[j] * wv[c];
    }

#pragma unroll
    for (int j = 0; j < 4; ++j) {
        int n = nbase + j;
        if (n < NNODES) {
            float4 r0 = make_float4(acc[j][0], acc[j][1], acc[j][2], acc[j][3]);
            float4 r1 = make_float4(acc[j][4], acc[j][5], acc[j][6], acc[j][7]);
            *(float4*)(out + (size_t)n * DIM + c0)     = r0;
            *(float4*)(out + (size_t)n * DIM + c0 + 4) = r1;
        }
    }
}

// ---------------- gather + epilogue (+ optional transposed write to hT) ----------
// out[n] = relu(mean_{d in N(n)} y[d] + z[n] + b);  z lives in `out` (in place).

__global__ __launch_bounds__(256) void gather_epi_kernel(
    const float* __restrict__ y, const int* __restrict__ rs,
    const int* __restrict__ re, const int* __restrict__ col,
    const float* __restrict__ b, float* __restrict__ out,
    float* __restrict__ hT, int writeT) {
    __shared__ __align__(16) float lds[8][100];
    int g = threadIdx.x >> 5;                 // 0..7 node within block
    int node = blockIdx.x * 8 + g;            // 6250*8 = 50000 exact
    int l = threadIdx.x & 31;

    if (l < 24) {
        int s = rs[node];
        int e = re[node];
        float4 acc = make_float4(0.f, 0.f, 0.f, 0.f);
        int i = s;
        for (; i + 1 < e; i += 2) {
            const float4* r0 = (const float4*)(y + (size_t)col[i] * DIM);
            const float4* r1 = (const float4*)(y + (size_t)col[i + 1] * DIM);
            float4 u = r0[l];
            float4 v = r1[l];
            acc.x += u.x + v.x; acc.y += u.y + v.y;
            acc.z += u.z + v.z; acc.w += u.w + v.w;
        }
        if (i < e) {
            float4 u = ((const float4*)(y + (size_t)col[i] * DIM))[l];
            acc.x += u.x; acc.y += u.y; acc.z += u.z; acc.w += u.w;
        }
        float scl = 1.0f / fmaxf((float)(e - s), 1.0f);
        float4 zv = ((const float4*)(out + (size_t)node * DIM))[l];
        float4 bv = ((const float4*)b)[l];
        float4 r;
        r.x = fmaxf(acc.x * scl + zv.x + bv.x, 0.0f);
        r.y = fmaxf(acc.y * scl + zv.y + bv.y, 0.0f);
        r.z = fmaxf(acc.z * scl + zv.z + bv.z, 0.0f);
        r.w = fmaxf(acc.w * scl + zv.w + bv.w, 0.0f);
        ((float4*)(out + (size_t)node * DIM))[l] = r;
        *(float4*)&lds[g][l * 4] = r;
    }
    if (writeT) {
        __syncthreads();
        int n0 = blockIdx.x * 8;
        for (int idx = threadIdx.x; idx < 8 * DIM; idx += 256) {
            int c = idx >> 3;
            int j = idx & 7;
            hT[(size_t)c * NPAD + n0 + j] = lds[j][c];
        }
    }
}

// ---------------- final linear: out = h @ lin_w + lin_b ----------------

__global__ __launch_bounds__(256) void final_kernel(
    const float* __restrict__ h, const float* __restrict__ LW,
    const float* __restrict__ LB, float* __restrict__ out) {
    __shared__ __align__(16) float Alds[96][68];
    __shared__ __align__(16) float Wlds[96][68];
    int tid = threadIdx.x;
    int q = tid & 15;
    int nb = tid >> 4;
    int n0 = blockIdx.x * 64;

    for (int idx = tid; idx < 64 * 24; idx += 256) {
        int row = idx & 63;
        int kq = idx >> 6;
        int rn = n0 + row;
        if (rn >= NNODES) rn = NNODES - 1;
        float4 v = *(const float4*)(h + (size_t)rn * DIM + kq * 4);
        Alds[kq * 4 + 0][row] = v.x;
        Alds[kq * 4 + 1][row] = v.y;
        Alds[kq * 4 + 2][row] = v.z;
        Alds[kq * 4 + 3][row] = v.w;
    }
    for (int idx = tid; idx < 96 * 16; idx += 256) {
        int kr = idx >> 4;
        int cq = idx & 15;
        *(float4*)&Wlds[kr][cq * 4] = *(const float4*)(LW + (size_t)kr * LLDIM + cq * 4);
    }
    __syncthreads();

    float acc[4][4];
#pragma unroll
    for (int j = 0; j < 4; ++j)
#pragma unroll
        for (int c = 0; c < 4; ++c) acc[j][c] = 0.0f;

#pragma unroll 4
    for (int k = 0; k < 96; ++k) {
        float4 a4 = *(float4*)&Alds[k][nb * 4];
        float4 w4 = *(float4*)&Wlds[k][q * 4];
        acc[0][0] += a4.x * w4.x; acc[0][1] += a4.x * w4.y;
        acc[0][2] += a4.x * w4.z; acc[0][3] += a4.x * w4.w;
        acc[1][0] += a4.y * w4.x; acc[1][1] += a4.y * w4.y;
        acc[1][2] += a4.y * w4.z; acc[1][3] += a4.y * w4.w;
        acc[2][0] += a4.z * w4.x; acc[2][1] += a4.z * w4.y;
        acc[2][2] += a4.z * w4.z; acc[2][3] += a4.z * w4.w;
        acc[3][0] += a4.w * w4.x; acc[3][1] += a4.w * w4.y;
        acc[3][2] += a4.w * w4.z; acc[3][3] += a4.w * w4.w;
    }

    float4 bv = *(const float4*)(LB + q * 4);
    int nbase = n0 + nb * 4;
#pragma unroll
    for (int j = 0; j < 4; ++j) {
        int n = nbase + j;
        if (n < NNODES) {
            float4 r;
            r.x = acc[j][0] + bv.x;
            r.y = acc[j][1] + bv.y;
            r.z = acc[j][2] + bv.z;
            r.w = acc[j][3] + bv.w;
            *(float4*)(out + (size_t)n * LLDIM + q * 4) = r;
        }
    }
}

extern "C" void kernel_launch(void* const* d_in, const int* in_sizes, int n_in,
                              void* d_out, int out_size, void* d_ws, size_t ws_size,
                              hipStream_t stream) {
    const float* x     = (const float*)d_in[0];
    const int*   ei    = (const int*)d_in[1];
    const int*   et    = (const int*)d_in[2];
    const float* w1    = (const float*)d_in[3];
    const float* root1 = (const float*)d_in[4];
    const float* b1    = (const float*)d_in[5];
    const float* w2    = (const float*)d_in[6];
    const float* root2 = (const float*)d_in[7];
    const float* b2    = (const float*)d_in[8];
    const float* lin_w = (const float*)d_in[9];
    const float* lin_b = (const float*)d_in[10];

    float* outRM = (float*)d_ws;                       // N*96  (z then layer out)
    float* ybuf  = outRM + (size_t)NNODES * DIM;       // N*96
    float* hT    = ybuf + (size_t)NNODES * DIM;        // 96*NPAD
    int* deg       = (int*)(hT + (size_t)DIM * NPAD);
    int* row_start = deg + SCAN_N;
    int* row_end   = row_start + SCAN_N;
    int* col       = row_end + SCAN_N;                 // up to NEDGES
    int* partials  = col + NEDGES;                     // 256

    const int edge_blocks = (NEDGES + 255) / 256;
    const int scan_blocks = (SCAN_N + 1023) / 1024;
    const int node_tiles  = (NNODES + 63) / 64;        // 782 (final kernel)
    const int gath_blocks = NNODES / 8;                // 6250 exact
    const int tg_blocks   = 56 * 24;                   // 1344 (XCD-swizzled, 49 real nb)
    const dim3 tr_grid((NNODES + 31) / 32, DIM / 32);

    // ---- CSR build ----
    hipMemsetAsync(deg, 0, SCAN_N * sizeof(int), stream);
    hist_kernel<<<edge_blocks, 256, 0, stream>>>(ei, et, deg);
    scan1_kernel<<<scan_blocks, 256, 0, stream>>>(deg, row_start, partials, SCAN_N);
    scan2_kernel<<<1, 256, 0, stream>>>(partials, scan_blocks);
    scan3_kernel<<<(SCAN_N + 255) / 256, 256, 0, stream>>>(row_start, row_end, partials, SCAN_N);
    fill_kernel<<<edge_blocks, 256, 0, stream>>>(ei, et, row_end, col);

    // ---- seed transposed input ----
    transpose_kernel<<<tr_grid, 256, 0, stream>>>(x, hT);

    // ---- Layer 0: rel 0 ----
    tgemm_kernel<<<tg_blocks, 256, 0, stream>>>(hT, w1, root1, ybuf, outRM);
    gather_epi_kernel<<<gath_blocks, 256, 0, stream>>>(
        ybuf, row_start + 0 * NNODES, row_end + 0 * NNODES, col, b1, outRM, hT, 1);

    // ---- Layer 1: rel 1 ----
    tgemm_kernel<<<tg_blocks, 256, 0, stream>>>(
        hT, w2 + (size_t)1 * DIM * DIM, root2, ybuf, outRM);
    gather_epi_kernel<<<gath_blocks, 256, 0, stream>>>(
        ybuf, row_start + 1 * NNODES, row_end + 1 * NNODES, col, b2, outRM, hT, 1);

    // ---- Layer 2: rel 2 (no transposed write needed) ----
    tgemm_kernel<<<tg_blocks, 256, 0, stream>>>(
        hT, w2 + (size_t)2 * DIM * DIM, root2, ybuf, outRM);
    gather_epi_kernel<<<gath_blocks, 256, 0, stream>>>(
        ybuf, row_start + 2 * NNODES, row_end + 2 * NNODES, col, b2, outRM, hT, 0);

    // ---- Final linear ----
    final_kernel<<<node_tiles, 256, 0, stream>>>(outRM, lin_w, lin_b, (float*)d_out);
}